// Round 1
// baseline (4622.540 us; speedup 1.0000x reference)
//
#include <hip/hip_runtime.h>
#include <hip/hip_bf16.h>
#include <hip/hip_cooperative_groups.h>

namespace cg = cooperative_groups;

#define TEMP_ 0.2f

static constexpr int RPC = 32;  // rows per chunk in colsum partials

// ---- bf16 helpers (manual, branch-free RNE; inputs are never NaN) ----
__device__ __forceinline__ float blo(unsigned int u){ return __uint_as_float(u << 16); }
__device__ __forceinline__ float bhi(unsigned int u){ return __uint_as_float(u & 0xFFFF0000u); }
__device__ __forceinline__ unsigned int pack2(float a, float b){
    unsigned int ua = __float_as_uint(a), ub = __float_as_uint(b);
    ua += 0x7FFFu + ((ua >> 16) & 1u);
    ub += 0x7FFFu + ((ub >> 16) & 1u);
    return (ua >> 16) | (ub & 0xFFFF0000u);
}

// r = 1, v = A (so A/v = 1 on first iteration); stats scalars init
__global__ void init_kernel(float* r, float* v, const float* __restrict__ Av, int N,
                            double* s, double* s2, int* mb){
    int i = blockIdx.x * blockDim.x + threadIdx.x;
    if (i < N){ r[i] = 1.0f; v[i] = Av[i]; }
    if (i == 0){ *s = 0.0; *s2 = 0.0; *mb = 0x7F800000; }
}

// sum, sumsq (fp64), min over all elements
__global__ void stats_kernel(const float* __restrict__ x, long long n4,
                             double* s, double* s2, int* mb){
    long long i = blockIdx.x * (long long)blockDim.x + threadIdx.x;
    long long stride = (long long)gridDim.x * blockDim.x;
    const float4* x4 = (const float4*)x;
    double a = 0.0, b = 0.0;
    float mn = __int_as_float(0x7F800000);
    for (; i < n4; i += stride){
        float4 v = x4[i];
        a += (double)v.x + (double)v.y + (double)v.z + (double)v.w;
        b += (double)v.x * v.x + (double)v.y * v.y + (double)v.z * v.z + (double)v.w * v.w;
        mn = fminf(mn, fminf(fminf(v.x, v.y), fminf(v.z, v.w)));
    }
    #pragma unroll
    for (int off = 32; off; off >>= 1){
        a  += __shfl_down(a, off);
        b  += __shfl_down(b, off);
        mn  = fminf(mn, __shfl_down(mn, off));
    }
    __shared__ double sa[4], sb[4]; __shared__ float sm[4];
    int w = threadIdx.x >> 6, l = threadIdx.x & 63;
    if (l == 0){ sa[w] = a; sb[w] = b; sm[w] = mn; }
    __syncthreads();
    if (threadIdx.x == 0){
        int nw = blockDim.x >> 6;
        for (int k = 1; k < nw; ++k){ a += sa[k]; b += sb[k]; mn = fminf(mn, sm[k]); }
        atomicAdd(s, a);
        atomicAdd(s2, b);
        atomicMin(mb, __float_as_int(mn));  // valid: all inputs >= 0
    }
}

// coefs[0] = 1/(std*TEMP), coefs[1] = min  =>  q = exp((min - x) * a)
__global__ void finalize_kernel(const double* s, const double* s2, const int* mb,
                                double n, float* coefs){
    double mean = *s / n;
    double var  = *s2 / n - mean * mean;
    double stdv = sqrt(var * (n / (n - 1.0)));   // unbiased (ddof=1)
    coefs[0] = (float)(1.0 / (stdv * (double)TEMP_));
    coefs[1] = __int_as_float(*mb);
}

// q~ = bf16(exp((min - x) * a)), 8 elements / thread
__global__ void build_q_kernel(const float* __restrict__ x, unsigned int* __restrict__ q,
                               const float* __restrict__ coefs, long long n){
    float a = coefs[0], mv = coefs[1];
    long long i = (blockIdx.x * (long long)blockDim.x + threadIdx.x) * 8;
    if (i >= n) return;
    float4 v0 = *(const float4*)(x + i);
    float4 v1 = *(const float4*)(x + i + 4);
    float q0 = __expf((mv - v0.x) * a), q1 = __expf((mv - v0.y) * a);
    float q2 = __expf((mv - v0.z) * a), q3 = __expf((mv - v0.w) * a);
    float q4 = __expf((mv - v1.x) * a), q5 = __expf((mv - v1.y) * a);
    float q6 = __expf((mv - v1.z) * a), q7 = __expf((mv - v1.w) * a);
    uint4 o;
    o.x = pack2(q0, q1); o.y = pack2(q2, q3); o.z = pack2(q4, q5); o.w = pack2(q6, q7);
    *(uint4*)(q + (i >> 1)) = o;
}

// ---------------------------------------------------------------------------
// Persistent cooperative kernel: all 10 Sinkhorn iterations, 3 grid syncs each.
//   Phase A: colsum partials P[rc][j] = sum_{rows in chunk} (A_i/v_i) * q_ij
//            (rowfin fused: rv computed from v in LDS per 32-row chunk)
//   Phase B: c[j] = B[j] / sum_rc P[rc][j]   (128 blocks x 64 cols, coalesced)
//   Phase C: v[i] = sum_j q_ij * c_j         (one wave per row)
// After loop: r[i] = A_i / v_i for the final T kernel.
// ---------------------------------------------------------------------------
__global__ __launch_bounds__(256, 4)
void sinkhorn_loop_kernel(const unsigned int* __restrict__ q,
                          const float* __restrict__ Av,
                          const float* __restrict__ Bv,
                          float* __restrict__ P,
                          float* __restrict__ c,
                          float* __restrict__ v,
                          float* __restrict__ r,
                          int N, int M, int n_it)
{
    cg::grid_group grid = cg::this_grid();
    const int tid   = threadIdx.x;
    const int nCol  = M / 2048;       // col groups (8 cols/thread * 256 threads)
    const int RC    = N / RPC;        // row chunks
    const int nTile = nCol * RC;
    const int NB    = gridDim.x;

    __shared__ float srv[RPC];
    __shared__ float sred[256];

    for (int it = 0; it < n_it; ++it){
        // ---- Phase A: weighted column-sum partials ----
        for (int tile = blockIdx.x; tile < nTile; tile += NB){
            int tx = tile % nCol, ty = tile / nCol;
            int j0   = tx * 2048 + tid * 8;
            int row0 = ty * RPC;
            __syncthreads();                       // srv reuse guard
            if (tid < RPC) srv[tid] = Av[row0 + tid] / v[row0 + tid];
            __syncthreads();
            float acc[8] = {0,0,0,0,0,0,0,0};
            for (int k = 0; k < RPC; ++k){
                float rv = srv[k];
                long long base = (long long)(row0 + k) * M + j0;
                uint4 qq = *(const uint4*)(q + (base >> 1));
                acc[0] += rv * blo(qq.x); acc[1] += rv * bhi(qq.x);
                acc[2] += rv * blo(qq.y); acc[3] += rv * bhi(qq.y);
                acc[4] += rv * blo(qq.z); acc[5] += rv * bhi(qq.z);
                acc[6] += rv * blo(qq.w); acc[7] += rv * bhi(qq.w);
            }
            float* Pr = P + (long long)ty * M + j0;
            *(float4*)(Pr)     = make_float4(acc[0], acc[1], acc[2], acc[3]);
            *(float4*)(Pr + 4) = make_float4(acc[4], acc[5], acc[6], acc[7]);
        }
        grid.sync();

        // ---- Phase B: column finalize (coalesced 64-col blocks, LDS reduce) ----
        for (int cb = blockIdx.x; cb < M / 64; cb += NB){
            int col = cb * 64 + (tid & 63);
            int w   = tid >> 6;                    // 4 waves split the rc range
            float s = 0.f;
            for (int k = 0; k < RC / 4; ++k)
                s += P[(long long)(w + 4 * k) * M + col];
            sred[tid] = s;
            __syncthreads();
            if (w == 0)
                c[col] = Bv[col] /
                         (sred[tid] + sred[tid + 64] + sred[tid + 128] + sred[tid + 192]);
            __syncthreads();
        }
        grid.sync();

        // ---- Phase C: row sums (one wave per row) ----
        {
            int wid   = (blockIdx.x * blockDim.x + tid) >> 6;
            int lane  = tid & 63;
            int nwave = (NB * blockDim.x) >> 6;
            for (int row = wid; row < N; row += nwave){
                long long base = (long long)row * M;
                float acc = 0.f;
                for (int j = lane * 8; j < M; j += 512){
                    float4 c0 = *(const float4*)(c + j);
                    float4 c1 = *(const float4*)(c + j + 4);
                    uint4 qq = *(const uint4*)(q + ((base + j) >> 1));
                    acc += blo(qq.x)*c0.x + bhi(qq.x)*c0.y + blo(qq.y)*c0.z + bhi(qq.y)*c0.w
                         + blo(qq.z)*c1.x + bhi(qq.z)*c1.y + blo(qq.w)*c1.z + bhi(qq.w)*c1.w;
                }
                #pragma unroll
                for (int off = 32; off; off >>= 1) acc += __shfl_down(acc, off);
                if (lane == 0) v[row] = acc;
            }
        }
        grid.sync();
    }

    // r_i = A_i / v_i for the final T kernel
    int g   = blockIdx.x * blockDim.x + tid;
    int tot = NB * blockDim.x;
    for (int i = g; i < N; i += tot) r[i] = Av[i] / v[i];
}

// ---------------- fallback (no Q cache) path, unchanged ----------------
template<bool USE_Q>
__global__ void colsum_kernel(const unsigned int* __restrict__ q, const float* __restrict__ x,
                              const float* __restrict__ coefs, const float* __restrict__ r,
                              float* __restrict__ P, int M){
    int j0   = blockIdx.x * 2048 + threadIdx.x * 8;
    int row0 = blockIdx.y * RPC;
    float a = 0.f, mv = 0.f;
    if (!USE_Q){ a = coefs[0]; mv = coefs[1]; }
    float acc[8] = {0,0,0,0,0,0,0,0};
    for (int it = 0; it < RPC; ++it){
        int row = row0 + it;
        float rv = r[row];
        long long base = (long long)row * M + j0;
        if (USE_Q){
            uint4 qq = *(const uint4*)(q + (base >> 1));
            acc[0] += rv * blo(qq.x); acc[1] += rv * bhi(qq.x);
            acc[2] += rv * blo(qq.y); acc[3] += rv * bhi(qq.y);
            acc[4] += rv * blo(qq.z); acc[5] += rv * bhi(qq.z);
            acc[6] += rv * blo(qq.w); acc[7] += rv * bhi(qq.w);
        } else {
            float4 v0 = *(const float4*)(x + base);
            float4 v1 = *(const float4*)(x + base + 4);
            acc[0] += rv * __expf((mv - v0.x) * a); acc[1] += rv * __expf((mv - v0.y) * a);
            acc[2] += rv * __expf((mv - v0.z) * a); acc[3] += rv * __expf((mv - v0.w) * a);
            acc[4] += rv * __expf((mv - v1.x) * a); acc[5] += rv * __expf((mv - v1.y) * a);
            acc[6] += rv * __expf((mv - v1.z) * a); acc[7] += rv * __expf((mv - v1.w) * a);
        }
    }
    float* Pr = P + (long long)blockIdx.y * M + j0;
    *(float4*)(Pr)     = make_float4(acc[0], acc[1], acc[2], acc[3]);
    *(float4*)(Pr + 4) = make_float4(acc[4], acc[5], acc[6], acc[7]);
}

__global__ void colfin_kernel(const float* __restrict__ Bv, const float* __restrict__ P,
                              float* __restrict__ c, int M, int RC){
    int j = blockIdx.x * blockDim.x + threadIdx.x;
    if (j >= M) return;
    float s = 0.f;
    for (int rc = 0; rc < RC; ++rc) s += P[(long long)rc * M + j];
    c[j] = Bv[j] / s;
}

template<bool USE_Q>
__global__ void rowsum_kernel(const unsigned int* __restrict__ q, const float* __restrict__ x,
                              const float* __restrict__ coefs, const float* __restrict__ c,
                              float* __restrict__ v, int M){
    int gid  = blockIdx.x * blockDim.x + threadIdx.x;
    int row  = gid >> 6;
    int lane = gid & 63;
    float a = 0.f, mv = 0.f;
    if (!USE_Q){ a = coefs[0]; mv = coefs[1]; }
    long long base = (long long)row * M;
    float acc = 0.f;
    for (int j = lane * 8; j < M; j += 512){
        float4 c0 = *(const float4*)(c + j);
        float4 c1 = *(const float4*)(c + j + 4);
        if (USE_Q){
            uint4 qq = *(const uint4*)(q + ((base + j) >> 1));
            acc += blo(qq.x) * c0.x + bhi(qq.x) * c0.y + blo(qq.y) * c0.z + bhi(qq.y) * c0.w
                 + blo(qq.z) * c1.x + bhi(qq.z) * c1.y + blo(qq.w) * c1.z + bhi(qq.w) * c1.w;
        } else {
            float4 v0 = *(const float4*)(x + base + j);
            float4 v1 = *(const float4*)(x + base + j + 4);
            acc += __expf((mv - v0.x) * a) * c0.x + __expf((mv - v0.y) * a) * c0.y
                 + __expf((mv - v0.z) * a) * c0.z + __expf((mv - v0.w) * a) * c0.w
                 + __expf((mv - v1.x) * a) * c1.x + __expf((mv - v1.y) * a) * c1.y
                 + __expf((mv - v1.z) * a) * c1.z + __expf((mv - v1.w) * a) * c1.w;
        }
    }
    #pragma unroll
    for (int off = 32; off; off >>= 1) acc += __shfl_down(acc, off);
    if (lane == 0) v[row] = acc;
}

__global__ void rowfin_kernel(const float* __restrict__ Av, const float* __restrict__ vv,
                              float* __restrict__ r, int N){
    int i = blockIdx.x * blockDim.x + threadIdx.x;
    if (i < N) r[i] = Av[i] / vv[i];
}

// T_ij = r_i * exp((min - x_ij)*a) * c_j  — exact exp from fp32 cdist
__global__ void final_kernel(const float* __restrict__ x, const float* __restrict__ coefs,
                             const float* __restrict__ r, const float* __restrict__ c,
                             float* __restrict__ out, int M){
    long long i = (blockIdx.x * (long long)blockDim.x + threadIdx.x) * 4;
    int row = (int)(i / M);
    int j   = (int)(i - (long long)row * M);
    float a = coefs[0], mv = coefs[1];
    float rv = r[row];
    float4 v  = *(const float4*)(x + i);
    float4 cc = *(const float4*)(c + j);
    float4 o;
    o.x = rv * cc.x * __expf((mv - v.x) * a);
    o.y = rv * cc.y * __expf((mv - v.y) * a);
    o.z = rv * cc.z * __expf((mv - v.z) * a);
    o.w = rv * cc.w * __expf((mv - v.w) * a);
    *(float4*)(out + i) = o;
}

extern "C" void kernel_launch(void* const* d_in, const int* in_sizes, int n_in,
                              void* d_out, int out_size, void* d_ws, size_t ws_size,
                              hipStream_t stream){
    const float* x  = (const float*)d_in[0];
    const float* Av = (const float*)d_in[1];
    const float* Bv = (const float*)d_in[2];
    float* out = (float*)d_out;
    int N = in_sizes[1], M = in_sizes[2];
    long long NM = (long long)N * M;

    char* ws = (char*)d_ws;
    double* s    = (double*)(ws + 0);
    double* s2   = (double*)(ws + 8);
    int*    mb   = (int*)   (ws + 16);
    float*  coefs= (float*) (ws + 24);
    size_t off = 64;
    float* v = (float*)(ws + off); off += (size_t)N * 4;
    float* r = (float*)(ws + off); off += (size_t)N * 4;
    float* c = (float*)(ws + off); off += (size_t)M * 4;
    int RC = N / RPC;
    float* P = (float*)(ws + off); off += (size_t)RC * M * 4;
    off = (off + 255) & ~(size_t)255;
    unsigned int* q = (unsigned int*)(ws + off);
    const bool use_q = (ws_size >= off + (size_t)NM * 2);  // bf16 Q cache fits?

    init_kernel<<<(N + 255) / 256, 256, 0, stream>>>(r, v, Av, N, s, s2, mb);
    stats_kernel<<<2048, 256, 0, stream>>>(x, NM >> 2, s, s2, mb);
    finalize_kernel<<<1, 1, 0, stream>>>(s, s2, mb, (double)NM, coefs);

    if (use_q){
        build_q_kernel<<<(int)(NM / 8 / 256), 256, 0, stream>>>(x, q, coefs, NM);

        // cooperative grid: capped at co-resident capacity (cached across calls)
        static int s_grid = -1;
        if (s_grid < 0){
            int dev = 0; hipGetDevice(&dev);
            hipDeviceProp_t prop;
            hipGetDeviceProperties(&prop, dev);
            int bpc = 0;
            hipOccupancyMaxActiveBlocksPerMultiprocessor(&bpc, sinkhorn_loop_kernel, 256, 0);
            if (bpc < 1) bpc = 1;
            long long cap = (long long)bpc * prop.multiProcessorCount;
            long long want = (long long)(M / 2048) * (N / RPC);   // 1024 tiles
            s_grid = (int)(cap < want ? cap : want);
        }

        const unsigned int* a0 = q;
        const float* a1 = Av; const float* a2 = Bv;
        float* a3 = P; float* a4 = c; float* a5 = v; float* a6 = r;
        int a7 = N, a8 = M, a9 = 10;
        void* args[] = {&a0, &a1, &a2, &a3, &a4, &a5, &a6, &a7, &a8, &a9};
        hipLaunchCooperativeKernel((void*)sinkhorn_loop_kernel,
                                   dim3(s_grid), dim3(256), args, 0, stream);
    } else {
        dim3 cgrid(M / 2048, RC);
        int rgrid = N / 4;
        for (int it = 0; it < 10; ++it){
            colsum_kernel<false><<<cgrid, 256, 0, stream>>>(q, x, coefs, r, P, M);
            colfin_kernel<<<(M + 255) / 256, 256, 0, stream>>>(Bv, P, c, M, RC);
            rowsum_kernel<false><<<rgrid, 256, 0, stream>>>(q, x, coefs, c, v, M);
            rowfin_kernel<<<(N + 255) / 256, 256, 0, stream>>>(Av, v, r, N);
        }
    }

    final_kernel<<<(int)(NM / 4 / 256), 256, 0, stream>>>(x, coefs, r, c, out, M);
}

// Round 2
// 1233.991 us; speedup vs baseline: 3.7460x; 3.7460x over previous
//
#include <hip/hip_runtime.h>
#include <hip/hip_bf16.h>

#define TEMP_ 0.2f

static constexpr int RPC = 32;  // rows per chunk in fallback colsum partials

// ---- bf16 helpers (manual, branch-free RNE; inputs are never NaN) ----
__device__ __forceinline__ float blo(unsigned int u){ return __uint_as_float(u << 16); }
__device__ __forceinline__ float bhi(unsigned int u){ return __uint_as_float(u & 0xFFFF0000u); }
__device__ __forceinline__ unsigned int pack2(float a, float b){
    unsigned int ua = __float_as_uint(a), ub = __float_as_uint(b);
    ua += 0x7FFFu + ((ua >> 16) & 1u);
    ub += 0x7FFFu + ((ub >> 16) & 1u);
    return (ua >> 16) | (ub & 0xFFFF0000u);
}

// r = 1, v = A (fallback path init); stats scalars init
__global__ void init_kernel(float* r, float* v, const float* __restrict__ Av, int N,
                            double* s, double* s2, int* mb){
    int i = blockIdx.x * blockDim.x + threadIdx.x;
    if (i < N){ r[i] = 1.0f; v[i] = Av[i]; }
    if (i == 0){ *s = 0.0; *s2 = 0.0; *mb = 0x7F800000; }
}

// sum, sumsq (fp64), min over all elements
__global__ void stats_kernel(const float* __restrict__ x, long long n4,
                             double* s, double* s2, int* mb){
    long long i = blockIdx.x * (long long)blockDim.x + threadIdx.x;
    long long stride = (long long)gridDim.x * blockDim.x;
    const float4* x4 = (const float4*)x;
    double a = 0.0, b = 0.0;
    float mn = __int_as_float(0x7F800000);
    for (; i < n4; i += stride){
        float4 v = x4[i];
        a += (double)v.x + (double)v.y + (double)v.z + (double)v.w;
        b += (double)v.x * v.x + (double)v.y * v.y + (double)v.z * v.z + (double)v.w * v.w;
        mn = fminf(mn, fminf(fminf(v.x, v.y), fminf(v.z, v.w)));
    }
    #pragma unroll
    for (int off = 32; off; off >>= 1){
        a  += __shfl_down(a, off);
        b  += __shfl_down(b, off);
        mn  = fminf(mn, __shfl_down(mn, off));
    }
    __shared__ double sa[4], sb[4]; __shared__ float sm[4];
    int w = threadIdx.x >> 6, l = threadIdx.x & 63;
    if (l == 0){ sa[w] = a; sb[w] = b; sm[w] = mn; }
    __syncthreads();
    if (threadIdx.x == 0){
        int nw = blockDim.x >> 6;
        for (int k = 1; k < nw; ++k){ a += sa[k]; b += sb[k]; mn = fminf(mn, sm[k]); }
        atomicAdd(s, a);
        atomicAdd(s2, b);
        atomicMin(mb, __float_as_int(mn));  // valid: all inputs >= 0
    }
}

// coefs[0] = 1/(std*TEMP), coefs[1] = min  =>  q = exp((min - x) * a)
__global__ void finalize_kernel(const double* s, const double* s2, const int* mb,
                                double n, float* coefs){
    double mean = *s / n;
    double var  = *s2 / n - mean * mean;
    double stdv = sqrt(var * (n / (n - 1.0)));   // unbiased (ddof=1)
    coefs[0] = (float)(1.0 / (stdv * (double)TEMP_));
    coefs[1] = __int_as_float(*mb);
}

// q~ = bf16(exp((min - x) * a)), 8 elements / thread
__global__ void build_q_kernel(const float* __restrict__ x, unsigned int* __restrict__ q,
                               const float* __restrict__ coefs, long long n){
    float a = coefs[0], mv = coefs[1];
    long long i = (blockIdx.x * (long long)blockDim.x + threadIdx.x) * 8;
    if (i >= n) return;
    float4 v0 = *(const float4*)(x + i);
    float4 v1 = *(const float4*)(x + i + 4);
    float q0 = __expf((mv - v0.x) * a), q1 = __expf((mv - v0.y) * a);
    float q2 = __expf((mv - v0.z) * a), q3 = __expf((mv - v0.w) * a);
    float q4 = __expf((mv - v1.x) * a), q5 = __expf((mv - v1.y) * a);
    float q6 = __expf((mv - v1.z) * a), q7 = __expf((mv - v1.w) * a);
    uint4 o;
    o.x = pack2(q0, q1); o.y = pack2(q2, q3); o.z = pack2(q4, q5); o.w = pack2(q6, q7);
    *(uint4*)(q + (i >> 1)) = o;
}

// ---------------------------------------------------------------------------
// gstep: one block owns an 8-row strip of Q, staged once in LDS (16*M bytes).
// MODE 0 (INIT): r=1, emit column partials P[chunk][j] only.
// MODE 1 (NORM): v_i = sum_j q_ij c_j (sweep 1), r_i = A_i/v_i locally,
//                emit P[chunk][j] = sum_i r_i q_ij (sweep 2). ONE Q read for both.
// MODE 2 (LAST): sweep 1 only; write r_i to global for the final T kernel.
// Block = 1024 threads (16 waves); 2 waves per row in sweep 1.
// ---------------------------------------------------------------------------
template<int MODE>
__global__ __launch_bounds__(1024)
void gstep_kernel(const unsigned int* __restrict__ q,
                  const float* __restrict__ Av,
                  const float* __restrict__ c,
                  float* __restrict__ P,
                  float* __restrict__ r,
                  int M)
{
    extern __shared__ uint4 ldsbuf[];
    unsigned int* lds = (unsigned int*)ldsbuf;
    __shared__ float sv[16];
    __shared__ float srv[8];
    const int tid = threadIdx.x;
    const int b   = blockIdx.x;

    // stage strip: 8 rows * M bf16 = 4*M uints = M uint4s, fully coalesced
    {
        const uint4* g4 = (const uint4*)(q + (long long)b * 4 * M);
        uint4* l4 = ldsbuf;
        for (int k = tid; k < M; k += 1024) l4[k] = g4[k];
    }
    __syncthreads();

    if (MODE != 0){
        // sweep 1: v_i = sum_j q_ij * c_j ; wave w -> row w>>1, half w&1
        int w = tid >> 6, lane = tid & 63;
        int row = w >> 1, half = w & 1;
        const uint4* lr = (const uint4*)(lds + row * (M >> 1));
        const int hstep = M >> 4;                 // uint4s per half-row
        float acc = 0.f;
        for (int idx = half * hstep + lane; idx < (half + 1) * hstep; idx += 64){
            uint4 qq = lr[idx];
            int j = idx * 8;
            float4 c0 = *(const float4*)(c + j);
            float4 c1 = *(const float4*)(c + j + 4);
            acc += blo(qq.x)*c0.x + bhi(qq.x)*c0.y + blo(qq.y)*c0.z + bhi(qq.y)*c0.w
                 + blo(qq.z)*c1.x + bhi(qq.z)*c1.y + blo(qq.w)*c1.z + bhi(qq.w)*c1.w;
        }
        #pragma unroll
        for (int off = 32; off; off >>= 1) acc += __shfl_down(acc, off);
        if (lane == 0) sv[w] = acc;
        __syncthreads();
        if (tid < 8){
            float rv = Av[b * 8 + tid] / (sv[2 * tid] + sv[2 * tid + 1]);
            srv[tid] = rv;
            if (MODE == 2) r[b * 8 + tid] = rv;
        }
        __syncthreads();
    } else {
        if (tid < 8) srv[tid] = 1.0f;
        __syncthreads();
    }

    if (MODE != 2){
        // sweep 2: P[b][j] = sum_{i<8} srv[i] * q_ij, thread owns 8 cols
        for (int j0 = tid * 8; j0 < M; j0 += 1024 * 8){
            float acc[8] = {0,0,0,0,0,0,0,0};
            #pragma unroll
            for (int i = 0; i < 8; ++i){
                uint4 qq = *(const uint4*)(lds + i * (M >> 1) + (j0 >> 1));
                float rv = srv[i];
                acc[0] += rv * blo(qq.x); acc[1] += rv * bhi(qq.x);
                acc[2] += rv * blo(qq.y); acc[3] += rv * bhi(qq.y);
                acc[4] += rv * blo(qq.z); acc[5] += rv * bhi(qq.z);
                acc[6] += rv * blo(qq.w); acc[7] += rv * bhi(qq.w);
            }
            float* Pr = P + (long long)b * M + j0;
            *(float4*)(Pr)     = make_float4(acc[0], acc[1], acc[2], acc[3]);
            *(float4*)(Pr + 4) = make_float4(acc[4], acc[5], acc[6], acc[7]);
        }
    }
}

// c_j = B_j / sum_rc P[rc][j] ; block = 64 cols, 1024 threads, 16-way rc split
__global__ __launch_bounds__(1024)
void colfin2_kernel(const float* __restrict__ Bv, const float* __restrict__ P,
                    float* __restrict__ c, int M, int RC){
    __shared__ float red[1024];
    int col = blockIdx.x * 64 + (threadIdx.x & 63);
    int w   = threadIdx.x >> 6;
    float s = 0.f;
    for (int k = w; k < RC; k += 16)
        s += P[(long long)k * M + col];
    red[threadIdx.x] = s;
    __syncthreads();
    if (w == 0){
        float t = 0.f;
        #pragma unroll
        for (int g = 0; g < 16; ++g) t += red[(threadIdx.x & 63) + 64 * g];
        c[col] = Bv[col] / t;
    }
}

// ---------------- fallback kernels (round-0 structure) ----------------
template<bool USE_Q>
__global__ void colsum_kernel(const unsigned int* __restrict__ q, const float* __restrict__ x,
                              const float* __restrict__ coefs, const float* __restrict__ r,
                              float* __restrict__ P, int M){
    int j0   = blockIdx.x * 2048 + threadIdx.x * 8;
    int row0 = blockIdx.y * RPC;
    float a = 0.f, mv = 0.f;
    if (!USE_Q){ a = coefs[0]; mv = coefs[1]; }
    float acc[8] = {0,0,0,0,0,0,0,0};
    for (int it = 0; it < RPC; ++it){
        int row = row0 + it;
        float rv = r[row];
        long long base = (long long)row * M + j0;
        if (USE_Q){
            uint4 qq = *(const uint4*)(q + (base >> 1));
            acc[0] += rv * blo(qq.x); acc[1] += rv * bhi(qq.x);
            acc[2] += rv * blo(qq.y); acc[3] += rv * bhi(qq.y);
            acc[4] += rv * blo(qq.z); acc[5] += rv * bhi(qq.z);
            acc[6] += rv * blo(qq.w); acc[7] += rv * bhi(qq.w);
        } else {
            float4 v0 = *(const float4*)(x + base);
            float4 v1 = *(const float4*)(x + base + 4);
            acc[0] += rv * __expf((mv - v0.x) * a); acc[1] += rv * __expf((mv - v0.y) * a);
            acc[2] += rv * __expf((mv - v0.z) * a); acc[3] += rv * __expf((mv - v0.w) * a);
            acc[4] += rv * __expf((mv - v1.x) * a); acc[5] += rv * __expf((mv - v1.y) * a);
            acc[6] += rv * __expf((mv - v1.z) * a); acc[7] += rv * __expf((mv - v1.w) * a);
        }
    }
    float* Pr = P + (long long)blockIdx.y * M + j0;
    *(float4*)(Pr)     = make_float4(acc[0], acc[1], acc[2], acc[3]);
    *(float4*)(Pr + 4) = make_float4(acc[4], acc[5], acc[6], acc[7]);
}

__global__ void colfin_kernel(const float* __restrict__ Bv, const float* __restrict__ P,
                              float* __restrict__ c, int M, int RC){
    int j = blockIdx.x * blockDim.x + threadIdx.x;
    if (j >= M) return;
    float s = 0.f;
    for (int rc = 0; rc < RC; ++rc) s += P[(long long)rc * M + j];
    c[j] = Bv[j] / s;
}

template<bool USE_Q>
__global__ void rowsum_kernel(const unsigned int* __restrict__ q, const float* __restrict__ x,
                              const float* __restrict__ coefs, const float* __restrict__ c,
                              float* __restrict__ v, int M){
    int gid  = blockIdx.x * blockDim.x + threadIdx.x;
    int row  = gid >> 6;
    int lane = gid & 63;
    float a = 0.f, mv = 0.f;
    if (!USE_Q){ a = coefs[0]; mv = coefs[1]; }
    long long base = (long long)row * M;
    float acc = 0.f;
    for (int j = lane * 8; j < M; j += 512){
        float4 c0 = *(const float4*)(c + j);
        float4 c1 = *(const float4*)(c + j + 4);
        if (USE_Q){
            uint4 qq = *(const uint4*)(q + ((base + j) >> 1));
            acc += blo(qq.x) * c0.x + bhi(qq.x) * c0.y + blo(qq.y) * c0.z + bhi(qq.y) * c0.w
                 + blo(qq.z) * c1.x + bhi(qq.z) * c1.y + blo(qq.w) * c1.z + bhi(qq.w) * c1.w;
        } else {
            float4 v0 = *(const float4*)(x + base + j);
            float4 v1 = *(const float4*)(x + base + j + 4);
            acc += __expf((mv - v0.x) * a) * c0.x + __expf((mv - v0.y) * a) * c0.y
                 + __expf((mv - v0.z) * a) * c0.z + __expf((mv - v0.w) * a) * c0.w
                 + __expf((mv - v1.x) * a) * c1.x + __expf((mv - v1.y) * a) * c1.y
                 + __expf((mv - v1.z) * a) * c1.z + __expf((mv - v1.w) * a) * c1.w;
        }
    }
    #pragma unroll
    for (int off = 32; off; off >>= 1) acc += __shfl_down(acc, off);
    if (lane == 0) v[row] = acc;
}

__global__ void rowfin_kernel(const float* __restrict__ Av, const float* __restrict__ vv,
                              float* __restrict__ r, int N){
    int i = blockIdx.x * blockDim.x + threadIdx.x;
    if (i < N) r[i] = Av[i] / vv[i];
}

// T_ij = r_i * exp((min - x_ij)*a) * c_j  — exact exp from fp32 cdist
__global__ void final_kernel(const float* __restrict__ x, const float* __restrict__ coefs,
                             const float* __restrict__ r, const float* __restrict__ c,
                             float* __restrict__ out, int M){
    long long i = (blockIdx.x * (long long)blockDim.x + threadIdx.x) * 4;
    int row = (int)(i / M);
    int j   = (int)(i - (long long)row * M);
    float a = coefs[0], mv = coefs[1];
    float rv = r[row];
    float4 v  = *(const float4*)(x + i);
    float4 cc = *(const float4*)(c + j);
    float4 o;
    o.x = rv * cc.x * __expf((mv - v.x) * a);
    o.y = rv * cc.y * __expf((mv - v.y) * a);
    o.z = rv * cc.z * __expf((mv - v.z) * a);
    o.w = rv * cc.w * __expf((mv - v.w) * a);
    *(float4*)(out + i) = o;
}

extern "C" void kernel_launch(void* const* d_in, const int* in_sizes, int n_in,
                              void* d_out, int out_size, void* d_ws, size_t ws_size,
                              hipStream_t stream){
    const float* x  = (const float*)d_in[0];
    const float* Av = (const float*)d_in[1];
    const float* Bv = (const float*)d_in[2];
    float* out = (float*)d_out;
    int N = in_sizes[1], M = in_sizes[2];
    long long NM = (long long)N * M;

    char* ws = (char*)d_ws;
    double* s    = (double*)(ws + 0);
    double* s2   = (double*)(ws + 8);
    int*    mb   = (int*)   (ws + 16);
    float*  coefs= (float*) (ws + 24);
    size_t off = 64;
    float* v = (float*)(ws + off); off += (size_t)N * 4;
    float* r = (float*)(ws + off); off += (size_t)N * 4;
    float* c = (float*)(ws + off); off += (size_t)M * 4;
    int RCg = N / 8;                       // gstep chunk count (8-row strips)
    float* P = (float*)(ws + off); off += (size_t)RCg * M * 4;   // covers fallback RC=N/32 too
    off = (off + 255) & ~(size_t)255;
    unsigned int* q = (unsigned int*)(ws + off);
    const bool use_q = (ws_size >= off + (size_t)NM * 2);  // bf16 Q cache fits?

    // raise dynamic-LDS limit for the 8-row strip kernels (once)
    static int s_attr = -1;
    if (s_attr < 0){
        hipError_t e0 = hipFuncSetAttribute(reinterpret_cast<const void*>(gstep_kernel<0>),
                                            hipFuncAttributeMaxDynamicSharedMemorySize, 131072);
        hipError_t e1 = hipFuncSetAttribute(reinterpret_cast<const void*>(gstep_kernel<1>),
                                            hipFuncAttributeMaxDynamicSharedMemorySize, 131072);
        hipError_t e2 = hipFuncSetAttribute(reinterpret_cast<const void*>(gstep_kernel<2>),
                                            hipFuncAttributeMaxDynamicSharedMemorySize, 131072);
        s_attr = (e0 == hipSuccess && e1 == hipSuccess && e2 == hipSuccess) ? 1 : 0;
    }
    const bool fast = use_q && s_attr == 1 &&
                      (M % 1024 == 0) && (M % 64 == 0) && (N % 8 == 0) &&
                      ((size_t)16 * M <= 131072);

    init_kernel<<<(N + 255) / 256, 256, 0, stream>>>(r, v, Av, N, s, s2, mb);
    stats_kernel<<<2048, 256, 0, stream>>>(x, NM >> 2, s, s2, mb);
    finalize_kernel<<<1, 1, 0, stream>>>(s, s2, mb, (double)NM, coefs);

    if (fast){
        const size_t ldsB = (size_t)16 * M;   // 8 rows * M bf16
        build_q_kernel<<<(int)(NM / 8 / 256), 256, 0, stream>>>(x, q, coefs, NM);
        gstep_kernel<0><<<RCg, 1024, ldsB, stream>>>(q, Av, c, P, r, M);
        for (int t = 1; t <= 10; ++t){
            colfin2_kernel<<<M / 64, 1024, 0, stream>>>(Bv, P, c, M, RCg);
            if (t < 10) gstep_kernel<1><<<RCg, 1024, ldsB, stream>>>(q, Av, c, P, r, M);
            else        gstep_kernel<2><<<RCg, 1024, ldsB, stream>>>(q, Av, c, P, r, M);
        }
    } else if (use_q){
        build_q_kernel<<<(int)(NM / 8 / 256), 256, 0, stream>>>(x, q, coefs, NM);
        dim3 cgrid(M / 2048, N / RPC);
        int rgrid = N / 4;
        for (int it = 0; it < 10; ++it){
            colsum_kernel<true ><<<cgrid, 256, 0, stream>>>(q, x, coefs, r, P, M);
            colfin_kernel<<<(M + 255) / 256, 256, 0, stream>>>(Bv, P, c, M, N / RPC);
            rowsum_kernel<true ><<<rgrid, 256, 0, stream>>>(q, x, coefs, c, v, M);
            rowfin_kernel<<<(N + 255) / 256, 256, 0, stream>>>(Av, v, r, N);
        }
    } else {
        dim3 cgrid(M / 2048, N / RPC);
        int rgrid = N / 4;
        for (int it = 0; it < 10; ++it){
            colsum_kernel<false><<<cgrid, 256, 0, stream>>>(q, x, coefs, r, P, M);
            colfin_kernel<<<(M + 255) / 256, 256, 0, stream>>>(Bv, P, c, M, N / RPC);
            rowsum_kernel<false><<<rgrid, 256, 0, stream>>>(q, x, coefs, c, v, M);
            rowfin_kernel<<<(N + 255) / 256, 256, 0, stream>>>(Av, v, r, N);
        }
    }

    final_kernel<<<(int)(NM / 4 / 256), 256, 0, stream>>>(x, coefs, r, c, out, M);
}

// Round 3
// 952.900 us; speedup vs baseline: 4.8510x; 1.2950x over previous
//
#include <hip/hip_runtime.h>
#include <hip/hip_bf16.h>

#define TEMP_ 0.2f

static constexpr int RPC = 32;  // rows per chunk in colsum partials (all paths)

// ---- bf16 helpers (manual, branch-free RNE; inputs are never NaN) ----
__device__ __forceinline__ float blo(unsigned int u){ return __uint_as_float(u << 16); }
__device__ __forceinline__ float bhi(unsigned int u){ return __uint_as_float(u & 0xFFFF0000u); }
__device__ __forceinline__ unsigned int pack2(float a, float b){
    unsigned int ua = __float_as_uint(a), ub = __float_as_uint(b);
    ua += 0x7FFFu + ((ua >> 16) & 1u);
    ub += 0x7FFFu + ((ub >> 16) & 1u);
    return (ua >> 16) | (ub & 0xFFFF0000u);
}

// r = 1, v = A (fallback path init); stats scalars init
__global__ void init_kernel(float* r, float* v, const float* __restrict__ Av, int N,
                            double* s, double* s2, int* mb){
    int i = blockIdx.x * blockDim.x + threadIdx.x;
    if (i < N){ r[i] = 1.0f; v[i] = Av[i]; }
    if (i == 0){ *s = 0.0; *s2 = 0.0; *mb = 0x7F800000; }
}

// sum, sumsq (fp64), min over all elements
__global__ void stats_kernel(const float* __restrict__ x, long long n4,
                             double* s, double* s2, int* mb){
    long long i = blockIdx.x * (long long)blockDim.x + threadIdx.x;
    long long stride = (long long)gridDim.x * blockDim.x;
    const float4* x4 = (const float4*)x;
    double a = 0.0, b = 0.0;
    float mn = __int_as_float(0x7F800000);
    for (; i < n4; i += stride){
        float4 v = x4[i];
        a += (double)v.x + (double)v.y + (double)v.z + (double)v.w;
        b += (double)v.x * v.x + (double)v.y * v.y + (double)v.z * v.z + (double)v.w * v.w;
        mn = fminf(mn, fminf(fminf(v.x, v.y), fminf(v.z, v.w)));
    }
    #pragma unroll
    for (int off = 32; off; off >>= 1){
        a  += __shfl_down(a, off);
        b  += __shfl_down(b, off);
        mn  = fminf(mn, __shfl_down(mn, off));
    }
    __shared__ double sa[4], sb[4]; __shared__ float sm[4];
    int w = threadIdx.x >> 6, l = threadIdx.x & 63;
    if (l == 0){ sa[w] = a; sb[w] = b; sm[w] = mn; }
    __syncthreads();
    if (threadIdx.x == 0){
        int nw = blockDim.x >> 6;
        for (int k = 1; k < nw; ++k){ a += sa[k]; b += sb[k]; mn = fminf(mn, sm[k]); }
        atomicAdd(s, a);
        atomicAdd(s2, b);
        atomicMin(mb, __float_as_int(mn));  // valid: all inputs >= 0
    }
}

// coefs[0] = 1/(std*TEMP), coefs[1] = min  =>  q = exp((min - x) * a)
__global__ void finalize_kernel(const double* s, const double* s2, const int* mb,
                                double n, float* coefs){
    double mean = *s / n;
    double var  = *s2 / n - mean * mean;
    double stdv = sqrt(var * (n / (n - 1.0)));   // unbiased (ddof=1)
    coefs[0] = (float)(1.0 / (stdv * (double)TEMP_));
    coefs[1] = __int_as_float(*mb);
}

// q~ = bf16(exp((min - x) * a)), 8 elements / thread
__global__ void build_q_kernel(const float* __restrict__ x, unsigned int* __restrict__ q,
                               const float* __restrict__ coefs, long long n){
    float a = coefs[0], mv = coefs[1];
    long long i = (blockIdx.x * (long long)blockDim.x + threadIdx.x) * 8;
    if (i >= n) return;
    float4 v0 = *(const float4*)(x + i);
    float4 v1 = *(const float4*)(x + i + 4);
    float q0 = __expf((mv - v0.x) * a), q1 = __expf((mv - v0.y) * a);
    float q2 = __expf((mv - v0.z) * a), q3 = __expf((mv - v0.w) * a);
    float q4 = __expf((mv - v1.x) * a), q5 = __expf((mv - v1.y) * a);
    float q6 = __expf((mv - v1.z) * a), q7 = __expf((mv - v1.w) * a);
    uint4 o;
    o.x = pack2(q0, q1); o.y = pack2(q2, q3); o.z = pack2(q4, q5); o.w = pack2(q6, q7);
    *(uint4*)(q + (i >> 1)) = o;
}

// ---------------------------------------------------------------------------
// gstep2: block owns 32 rows = 8 strips of 4 rows; double-buffered LDS (2x64KB).
// Per strip: issue next strip's global loads into REGISTERS (issue-early),
// compute sweep1 (v) + sweep2 (P accumulate in regs) on current strip,
// then write regs->LDS after the end barrier (write-late, T14).
// Intra-strip sync after sweep1 is a raw s_barrier + lgkmcnt(0) ONLY, so the
// prefetch loads stay in flight (no vmcnt drain).
// MODE 0: rv=1, sweep2 only. MODE 1: sweep1 + sweep2. MODE 2: sweep1 only, writes r.
// P chunk = 32 rows (register-accumulated) -> 8 MB total.
// Fast path fixed at M == 8192 (bench shape); fallbacks handle the rest.
// ---------------------------------------------------------------------------
template<int MODE>
__global__ __launch_bounds__(1024)
void gstep2_kernel(const unsigned int* __restrict__ qg,
                   const float* __restrict__ Av,
                   const float* __restrict__ cg,
                   float* __restrict__ P,
                   float* __restrict__ r)
{
    constexpr int FM  = 8192;          // columns (fast path)
    constexpr int RU4 = FM / 8;        // uint4 per row  = 1024
    constexpr int SU4 = 4 * RU4;       // uint4 per strip = 4096 (64 KB)
    extern __shared__ uint4 lds4[];    // two strip buffers
    __shared__ float sv[16];

    const int tid  = threadIdx.x;
    const int b    = blockIdx.x;
    const int w    = tid >> 6, lane = tid & 63;
    const uint4* g4 = (const uint4*)qg + (long long)b * 8 * SU4;

    // prologue: stage strip 0 (unoverlapped)
    {
        uint4 p0 = g4[tid], p1 = g4[tid + 1024], p2 = g4[tid + 2048], p3 = g4[tid + 3072];
        lds4[tid] = p0; lds4[tid + 1024] = p1; lds4[tid + 2048] = p2; lds4[tid + 3072] = p3;
    }
    __syncthreads();

    float acc[8] = {0,0,0,0,0,0,0,0};

    for (int s = 0; s < 8; ++s){
        const uint4* cur = lds4 + (s & 1) * SU4;
        uint4*       nxt = lds4 + ((s + 1) & 1) * SU4;
        uint4 p0, p1, p2, p3;
        const bool pf = (s + 1 < 8);
        if (pf){
            const uint4* gn = g4 + (long long)(s + 1) * SU4;
            p0 = gn[tid]; p1 = gn[tid + 1024]; p2 = gn[tid + 2048]; p3 = gn[tid + 3072];
        }

        float rv0 = 1.f, rv1 = 1.f, rv2 = 1.f, rv3 = 1.f;
        if (MODE != 0){
            // sweep1: v for 4 rows; 4 waves per row, each wave a quarter-row
            int row = w >> 2, quar = w & 3;
            const uint4* lr = cur + row * RU4 + quar * 256;
            float a1 = 0.f;
            #pragma unroll
            for (int k = 0; k < 4; ++k){
                uint4 qq = lr[lane + k * 64];
                int j = (quar * 256 + lane + k * 64) * 8;
                float4 c0 = *(const float4*)(cg + j);
                float4 c1 = *(const float4*)(cg + j + 4);
                a1 += blo(qq.x)*c0.x + bhi(qq.x)*c0.y + blo(qq.y)*c0.z + bhi(qq.y)*c0.w
                    + blo(qq.z)*c1.x + bhi(qq.z)*c1.y + blo(qq.w)*c1.z + bhi(qq.w)*c1.w;
            }
            #pragma unroll
            for (int off = 32; off; off >>= 1) a1 += __shfl_down(a1, off);
            if (lane == 0) sv[w] = a1;
            // raw barrier: lgkmcnt only — do NOT drain the prefetch vmcnt
            asm volatile("s_waitcnt lgkmcnt(0)" ::: "memory");
            __builtin_amdgcn_s_barrier();
            __builtin_amdgcn_sched_barrier(0);
            // every thread computes the 4 row scalings (redundant, no 2nd barrier)
            const float* Ab = Av + b * 32 + s * 4;
            rv0 = Ab[0] / (sv[0]  + sv[1]  + sv[2]  + sv[3]);
            rv1 = Ab[1] / (sv[4]  + sv[5]  + sv[6]  + sv[7]);
            rv2 = Ab[2] / (sv[8]  + sv[9]  + sv[10] + sv[11]);
            rv3 = Ab[3] / (sv[12] + sv[13] + sv[14] + sv[15]);
            if (MODE == 2 && tid < 4){
                float rr = (tid == 0) ? rv0 : (tid == 1) ? rv1 : (tid == 2) ? rv2 : rv3;
                r[b * 32 + s * 4 + tid] = rr;
            }
        }

        if (MODE != 2){
            // sweep2: accumulate column partials for this thread's 8 columns
            uint4 q0 = cur[tid];
            uint4 q1 = cur[RU4 + tid];
            uint4 q2 = cur[2 * RU4 + tid];
            uint4 q3 = cur[3 * RU4 + tid];
            acc[0] += rv0*blo(q0.x) + rv1*blo(q1.x) + rv2*blo(q2.x) + rv3*blo(q3.x);
            acc[1] += rv0*bhi(q0.x) + rv1*bhi(q1.x) + rv2*bhi(q2.x) + rv3*bhi(q3.x);
            acc[2] += rv0*blo(q0.y) + rv1*blo(q1.y) + rv2*blo(q2.y) + rv3*blo(q3.y);
            acc[3] += rv0*bhi(q0.y) + rv1*bhi(q1.y) + rv2*bhi(q2.y) + rv3*bhi(q3.y);
            acc[4] += rv0*blo(q0.z) + rv1*blo(q1.z) + rv2*blo(q2.z) + rv3*blo(q3.z);
            acc[5] += rv0*bhi(q0.z) + rv1*bhi(q1.z) + rv2*bhi(q2.z) + rv3*bhi(q3.z);
            acc[6] += rv0*blo(q0.w) + rv1*blo(q1.w) + rv2*blo(q2.w) + rv3*blo(q3.w);
            acc[7] += rv0*bhi(q0.w) + rv1*bhi(q1.w) + rv2*bhi(q2.w) + rv3*bhi(q3.w);
        }

        __syncthreads();            // all reads of cur done; prefetch drained here
        if (pf){
            nxt[tid] = p0; nxt[tid + 1024] = p1; nxt[tid + 2048] = p2; nxt[tid + 3072] = p3;
            __syncthreads();        // staged strip visible for next iteration
        }
    }

    if (MODE != 2){
        float* Pr = P + (long long)b * FM + tid * 8;
        *(float4*)(Pr)     = make_float4(acc[0], acc[1], acc[2], acc[3]);
        *(float4*)(Pr + 4) = make_float4(acc[4], acc[5], acc[6], acc[7]);
    }
}

// c_j = B_j / sum_rc P[rc][j] ; block = 64 cols, 1024 threads, 16-way rc split
__global__ __launch_bounds__(1024)
void colfin2_kernel(const float* __restrict__ Bv, const float* __restrict__ P,
                    float* __restrict__ c, int M, int RC){
    __shared__ float red[1024];
    int col = blockIdx.x * 64 + (threadIdx.x & 63);
    int w   = threadIdx.x >> 6;
    float s = 0.f;
    for (int k = w; k < RC; k += 16)
        s += P[(long long)k * M + col];
    red[threadIdx.x] = s;
    __syncthreads();
    if (w == 0){
        float t = 0.f;
        #pragma unroll
        for (int g = 0; g < 16; ++g) t += red[(threadIdx.x & 63) + 64 * g];
        c[col] = Bv[col] / t;
    }
}

// ---------------- fallback kernels (round-0 structure) ----------------
template<bool USE_Q>
__global__ void colsum_kernel(const unsigned int* __restrict__ q, const float* __restrict__ x,
                              const float* __restrict__ coefs, const float* __restrict__ r,
                              float* __restrict__ P, int M){
    int j0   = blockIdx.x * 2048 + threadIdx.x * 8;
    int row0 = blockIdx.y * RPC;
    float a = 0.f, mv = 0.f;
    if (!USE_Q){ a = coefs[0]; mv = coefs[1]; }
    float acc[8] = {0,0,0,0,0,0,0,0};
    for (int it = 0; it < RPC; ++it){
        int row = row0 + it;
        float rv = r[row];
        long long base = (long long)row * M + j0;
        if (USE_Q){
            uint4 qq = *(const uint4*)(q + (base >> 1));
            acc[0] += rv * blo(qq.x); acc[1] += rv * bhi(qq.x);
            acc[2] += rv * blo(qq.y); acc[3] += rv * bhi(qq.y);
            acc[4] += rv * blo(qq.z); acc[5] += rv * bhi(qq.z);
            acc[6] += rv * blo(qq.w); acc[7] += rv * bhi(qq.w);
        } else {
            float4 v0 = *(const float4*)(x + base);
            float4 v1 = *(const float4*)(x + base + 4);
            acc[0] += rv * __expf((mv - v0.x) * a); acc[1] += rv * __expf((mv - v0.y) * a);
            acc[2] += rv * __expf((mv - v0.z) * a); acc[3] += rv * __expf((mv - v0.w) * a);
            acc[4] += rv * __expf((mv - v1.x) * a); acc[5] += rv * __expf((mv - v1.y) * a);
            acc[6] += rv * __expf((mv - v1.z) * a); acc[7] += rv * __expf((mv - v1.w) * a);
        }
    }
    float* Pr = P + (long long)blockIdx.y * M + j0;
    *(float4*)(Pr)     = make_float4(acc[0], acc[1], acc[2], acc[3]);
    *(float4*)(Pr + 4) = make_float4(acc[4], acc[5], acc[6], acc[7]);
}

__global__ void colfin_kernel(const float* __restrict__ Bv, const float* __restrict__ P,
                              float* __restrict__ c, int M, int RC){
    int j = blockIdx.x * blockDim.x + threadIdx.x;
    if (j >= M) return;
    float s = 0.f;
    for (int rc = 0; rc < RC; ++rc) s += P[(long long)rc * M + j];
    c[j] = Bv[j] / s;
}

template<bool USE_Q>
__global__ void rowsum_kernel(const unsigned int* __restrict__ q, const float* __restrict__ x,
                              const float* __restrict__ coefs, const float* __restrict__ c,
                              float* __restrict__ v, int M){
    int gid  = blockIdx.x * blockDim.x + threadIdx.x;
    int row  = gid >> 6;
    int lane = gid & 63;
    float a = 0.f, mv = 0.f;
    if (!USE_Q){ a = coefs[0]; mv = coefs[1]; }
    long long base = (long long)row * M;
    float acc = 0.f;
    for (int j = lane * 8; j < M; j += 512){
        float4 c0 = *(const float4*)(c + j);
        float4 c1 = *(const float4*)(c + j + 4);
        if (USE_Q){
            uint4 qq = *(const uint4*)(q + ((base + j) >> 1));
            acc += blo(qq.x) * c0.x + bhi(qq.x) * c0.y + blo(qq.y) * c0.z + bhi(qq.y) * c0.w
                 + blo(qq.z) * c1.x + bhi(qq.z) * c1.y + blo(qq.w) * c1.z + bhi(qq.w) * c1.w;
        } else {
            float4 v0 = *(const float4*)(x + base + j);
            float4 v1 = *(const float4*)(x + base + j + 4);
            acc += __expf((mv - v0.x) * a) * c0.x + __expf((mv - v0.y) * a) * c0.y
                 + __expf((mv - v0.z) * a) * c0.z + __expf((mv - v0.w) * a) * c0.w
                 + __expf((mv - v1.x) * a) * c1.x + __expf((mv - v1.y) * a) * c1.y
                 + __expf((mv - v1.z) * a) * c1.z + __expf((mv - v1.w) * a) * c1.w;
        }
    }
    #pragma unroll
    for (int off = 32; off; off >>= 1) acc += __shfl_down(acc, off);
    if (lane == 0) v[row] = acc;
}

__global__ void rowfin_kernel(const float* __restrict__ Av, const float* __restrict__ vv,
                              float* __restrict__ r, int N){
    int i = blockIdx.x * blockDim.x + threadIdx.x;
    if (i < N) r[i] = Av[i] / vv[i];
}

// T_ij = r_i * exp((min - x_ij)*a) * c_j  — exact exp from fp32 cdist
__global__ void final_kernel(const float* __restrict__ x, const float* __restrict__ coefs,
                             const float* __restrict__ r, const float* __restrict__ c,
                             float* __restrict__ out, int M){
    long long i = (blockIdx.x * (long long)blockDim.x + threadIdx.x) * 4;
    int row = (int)(i / M);
    int j   = (int)(i - (long long)row * M);
    float a = coefs[0], mv = coefs[1];
    float rv = r[row];
    float4 v  = *(const float4*)(x + i);
    float4 cc = *(const float4*)(c + j);
    float4 o;
    o.x = rv * cc.x * __expf((mv - v.x) * a);
    o.y = rv * cc.y * __expf((mv - v.y) * a);
    o.z = rv * cc.z * __expf((mv - v.z) * a);
    o.w = rv * cc.w * __expf((mv - v.w) * a);
    *(float4*)(out + i) = o;
}

extern "C" void kernel_launch(void* const* d_in, const int* in_sizes, int n_in,
                              void* d_out, int out_size, void* d_ws, size_t ws_size,
                              hipStream_t stream){
    const float* x  = (const float*)d_in[0];
    const float* Av = (const float*)d_in[1];
    const float* Bv = (const float*)d_in[2];
    float* out = (float*)d_out;
    int N = in_sizes[1], M = in_sizes[2];
    long long NM = (long long)N * M;

    char* ws = (char*)d_ws;
    double* s    = (double*)(ws + 0);
    double* s2   = (double*)(ws + 8);
    int*    mb   = (int*)   (ws + 16);
    float*  coefs= (float*) (ws + 24);
    size_t off = 64;
    float* v = (float*)(ws + off); off += (size_t)N * 4;
    float* r = (float*)(ws + off); off += (size_t)N * 4;
    float* c = (float*)(ws + off); off += (size_t)M * 4;
    int RC = N / RPC;                       // 32-row chunks (fast + fallback)
    float* P = (float*)(ws + off); off += (size_t)RC * M * 4;
    off = (off + 255) & ~(size_t)255;
    unsigned int* q = (unsigned int*)(ws + off);
    const bool use_q = (ws_size >= off + (size_t)NM * 2);  // bf16 Q cache fits?

    // raise dynamic-LDS limit for the strip kernels (once)
    static int s_attr = -1;
    if (s_attr < 0){
        hipError_t e0 = hipFuncSetAttribute(reinterpret_cast<const void*>(gstep2_kernel<0>),
                                            hipFuncAttributeMaxDynamicSharedMemorySize, 131072);
        hipError_t e1 = hipFuncSetAttribute(reinterpret_cast<const void*>(gstep2_kernel<1>),
                                            hipFuncAttributeMaxDynamicSharedMemorySize, 131072);
        hipError_t e2 = hipFuncSetAttribute(reinterpret_cast<const void*>(gstep2_kernel<2>),
                                            hipFuncAttributeMaxDynamicSharedMemorySize, 131072);
        s_attr = (e0 == hipSuccess && e1 == hipSuccess && e2 == hipSuccess) ? 1 : 0;
    }
    const bool fast = use_q && s_attr == 1 && (M == 8192) && (N % 32 == 0);

    init_kernel<<<(N + 255) / 256, 256, 0, stream>>>(r, v, Av, N, s, s2, mb);
    stats_kernel<<<2048, 256, 0, stream>>>(x, NM >> 2, s, s2, mb);
    finalize_kernel<<<1, 1, 0, stream>>>(s, s2, mb, (double)NM, coefs);

    if (fast){
        const size_t ldsB = 131072;   // 2 x 64 KB strip buffers
        build_q_kernel<<<(int)(NM / 8 / 256), 256, 0, stream>>>(x, q, coefs, NM);
        gstep2_kernel<0><<<N / 32, 1024, ldsB, stream>>>(q, Av, c, P, r);
        for (int t = 1; t <= 10; ++t){
            colfin2_kernel<<<M / 64, 1024, 0, stream>>>(Bv, P, c, M, RC);
            if (t < 10) gstep2_kernel<1><<<N / 32, 1024, ldsB, stream>>>(q, Av, c, P, r);
            else        gstep2_kernel<2><<<N / 32, 1024, ldsB, stream>>>(q, Av, c, P, r);
        }
    } else if (use_q){
        build_q_kernel<<<(int)(NM / 8 / 256), 256, 0, stream>>>(x, q, coefs, NM);
        dim3 cgrid(M / 2048, RC);
        int rgrid = N / 4;
        for (int it = 0; it < 10; ++it){
            colsum_kernel<true ><<<cgrid, 256, 0, stream>>>(q, x, coefs, r, P, M);
            colfin_kernel<<<(M + 255) / 256, 256, 0, stream>>>(Bv, P, c, M, RC);
            rowsum_kernel<true ><<<rgrid, 256, 0, stream>>>(q, x, coefs, c, v, M);
            rowfin_kernel<<<(N + 255) / 256, 256, 0, stream>>>(Av, v, r, N);
        }
    } else {
        dim3 cgrid(M / 2048, RC);
        int rgrid = N / 4;
        for (int it = 0; it < 10; ++it){
            colsum_kernel<false><<<cgrid, 256, 0, stream>>>(q, x, coefs, r, P, M);
            colfin_kernel<<<(M + 255) / 256, 256, 0, stream>>>(Bv, P, c, M, RC);
            rowsum_kernel<false><<<rgrid, 256, 0, stream>>>(q, x, coefs, c, v, M);
            rowfin_kernel<<<(N + 255) / 256, 256, 0, stream>>>(Av, v, r, N);
        }
    }

    final_kernel<<<(int)(NM / 4 / 256), 256, 0, stream>>>(x, coefs, r, c, out, M);
}